// Round 4
// baseline (15090.074 us; speedup 1.0000x reference)
//
#include <hip/hip_runtime.h>
#include <math.h>

// ---------------- problem constants ----------------
#define NB 8
#define NMELS 80
#define TT 512
#define NFREQ 401
#define NFFT 800
#define HOPSZ 200
#define NROWS (NB*TT)          // 4096 frames
#define LY 103000              // untrimmed istft length (800 + 200*511)
#define LOUTW 102200           // trimmed per-batch output length
#define PADW 400
#define NSPEC (NROWS*NFREQ)    // 1640448
#define HALFN (NSPEC/2)
#define GLITERS 30
#define SGDITERS 50
#define SGD_SCALE 0.003125f    // 2/(B*n_mels)

#define PRNG_PARTITIONABLE 1

#define TWO_PI_D 6.283185307179586476925286766559

// ---------------- threefry2x32 (20 rounds) ----------------
__host__ __device__ inline void tf2x32(unsigned k0, unsigned k1,
                                       unsigned x0, unsigned x1,
                                       unsigned& o0, unsigned& o1) {
  unsigned ks0 = k0, ks1 = k1, ks2 = k0 ^ k1 ^ 0x1BD11BDAu;
  x0 += ks0; x1 += ks1;
#define TF_R(r) { x0 += x1; x1 = (x1 << (r)) | (x1 >> (32 - (r))); x1 ^= x0; }
  TF_R(13) TF_R(15) TF_R(26) TF_R(6)
  x0 += ks1; x1 += ks2 + 1u;
  TF_R(17) TF_R(29) TF_R(16) TF_R(24)
  x0 += ks2; x1 += ks0 + 2u;
  TF_R(13) TF_R(15) TF_R(26) TF_R(6)
  x0 += ks0; x1 += ks1 + 3u;
  TF_R(17) TF_R(29) TF_R(16) TF_R(24)
  x0 += ks1; x1 += ks2 + 4u;
  TF_R(13) TF_R(15) TF_R(26) TF_R(6)
  x0 += ks2; x1 += ks0 + 5u;
#undef TF_R
  o0 = x0; o1 = x1;
}

__device__ inline float u01(unsigned bits) {
  unsigned u = (bits >> 9) | 0x3f800000u;       // jax uniform: [1,2) - 1
  return __uint_as_float(u) - 1.0f;
}

// angle arrays generated in (B, F, T) flat order; our storage is (B, T, F)
__device__ inline int ang_map(int g) {
  int b = g / (NFREQ * TT);
  int r = g - b * (NFREQ * TT);
  int f = r / TT;
  int t = r - f * TT;
  return (b * TT + t) * NFREQ + f;
}

__global__ void k_rand_spec(unsigned ka, unsigned kb, float* __restrict__ spec) {
#if PRNG_PARTITIONABLE
  int i = blockIdx.x * blockDim.x + threadIdx.x;
  if (i >= NSPEC) return;
  unsigned o0, o1; tf2x32(ka, kb, 0u, (unsigned)i, o0, o1);
  spec[i] = u01(o0 ^ o1);    // partitionable 32-bit fold: bits1 ^ bits2
#else
  int i = blockIdx.x * blockDim.x + threadIdx.x;
  if (i >= HALFN) return;
  unsigned o0, o1; tf2x32(ka, kb, (unsigned)i, (unsigned)(i + HALFN), o0, o1);
  spec[i] = u01(o0);
  spec[i + HALFN] = u01(o1);
#endif
}

__global__ void k_rand_ang(unsigned kra, unsigned krb, unsigned kia, unsigned kib,
                           float* __restrict__ ar, float* __restrict__ ai) {
#if PRNG_PARTITIONABLE
  int g = blockIdx.x * blockDim.x + threadIdx.x;
  if (g >= NSPEC) return;
  int d = ang_map(g);
  unsigned o0, o1;
  tf2x32(kra, krb, 0u, (unsigned)g, o0, o1); ar[d] = u01(o0 ^ o1);
  tf2x32(kia, kib, 0u, (unsigned)g, o0, o1); ai[d] = u01(o0 ^ o1);
#else
  int g = blockIdx.x * blockDim.x + threadIdx.x;
  if (g >= HALFN) return;
  int d0 = ang_map(g), d1 = ang_map(g + HALFN);
  unsigned o0, o1;
  tf2x32(kra, krb, (unsigned)g, (unsigned)(g + HALFN), o0, o1);
  ar[d0] = u01(o0); ar[d1] = u01(o1);
  tf2x32(kia, kib, (unsigned)g, (unsigned)(g + HALFN), o0, o1);
  ai[d0] = u01(o0); ai[d1] = u01(o1);
#endif
}

// ---------------- mel filterbank (htk, norm=None), fp64 like numpy ----------------
__device__ inline double mel2hz_d(double mel) {
  return 700.0 * (pow(10.0, mel / 2595.0) - 1.0);
}

__global__ void k_fb(float* __restrict__ fbT, int* __restrict__ fm0,
                     float* __restrict__ fw0, float* __restrict__ fw1) {
  int f = blockIdx.x * blockDim.x + threadIdx.x;
  if (f >= NFREQ) return;
  const double freq = 10.0 * (double)f;                       // linspace(0,4000,401)
  const double melmax = 2595.0 * log10(1.0 + 4000.0 / 700.0);
  const double step = melmax / 81.0;
  int first = -1; float w0v = 0.f, w1v = 0.f;
  double p0 = 0.0;                  // f_pts[0]
  double p1 = mel2hz_d(step);       // f_pts[1]
  for (int m = 0; m < NMELS; ++m) {
    double m2 = (m + 2 == 81) ? melmax : (double)(m + 2) * step;
    double p2 = mel2hz_d(m2);
    double down = (freq - p0) / (p1 - p0);
    double up   = (p2 - freq) / (p2 - p1);
    double v = down < up ? down : up;
    if (v < 0.0) v = 0.0;
    float vf = (float)v;
    fbT[m * NFREQ + f] = vf;
    if (vf > 0.f) {
      if (first < 0) { first = m; w0v = vf; }
      else if (m == first + 1) { w1v = vf; }
    }
    p0 = p1; p1 = p2;
  }
  fm0[f] = first < 0 ? 0 : first;
  fw0[f] = first < 0 ? 0.f : w0v;
  fw1[f] = w1v;
}

__global__ void k_ranges(const float* __restrict__ fbT, int* __restrict__ mlo,
                         int* __restrict__ mhi) {
  int m = threadIdx.x;
  if (m >= NMELS) return;
  int lo = NFREQ, hi = 0;
  for (int f = 0; f < NFREQ; ++f)
    if (fbT[m * NFREQ + f] > 0.f) { if (lo == NFREQ) lo = f; hi = f + 1; }
  mlo[m] = lo; mhi[m] = hi < lo ? lo : hi;
}

// ---------------- window + overlap-add weight ----------------
__device__ inline double hann_d(int i) {
  return 0.5 - 0.5 * cos(TWO_PI_D * (double)i / 800.0);
}

__global__ void k_wsq(float* __restrict__ wsq, float* __restrict__ win,
                      double* __restrict__ wind) {
  int j = blockIdx.x * blockDim.x + threadIdx.x;
  if (j >= LY) return;
  if (j < NFFT) { double h = hann_d(j); win[j] = (float)h; wind[j] = h; }
  int t1 = j / HOPSZ; if (t1 > TT - 1) t1 = TT - 1;
  int t0 = (j - (NFFT - HOPSZ)) / HOPSZ; if (t0 < 0) t0 = 0;
  float s = 0.f;
  for (int t = t0; t <= t1; ++t) {
    float w = (float)hann_d(j - t * HOPSZ);
    s += w * w;
  }
  wsq[j] = fmaxf(s, 1e-11f);
}

// ---------------- DFT tables (fp64) ----------------
// irfft (window & 1/N & Hermitian x2 folded): frame[n] = sum_k Re*Cc + Im*Cs
__global__ void k_tab_ir(double* __restrict__ Cc, double* __restrict__ Cs) {
  int idx = blockIdx.x * blockDim.x + threadIdx.x;
  if (idx >= NFREQ * NFFT) return;
  int k = idx / NFFT, n = idx - k * NFFT;
  int ph = (k * n) % NFFT;
  double ang = (double)ph * (TWO_PI_D / 800.0);
  double wn = hann_d(n);
  bool edge = (k == 0) || (k == 400);
  double ak = edge ? 1.0 : 2.0;
  Cc[idx] = ak * cos(ang) * wn / 800.0;
  Cs[idx] = edge ? 0.0 : (-2.0 * sin(ang) * wn / 800.0);
}

// rfft: X[k] = sum_n x[n]*(cos - i sin)
__global__ void k_tab_r(double* __restrict__ Tc, double* __restrict__ Ts) {
  int idx = blockIdx.x * blockDim.x + threadIdx.x;
  if (idx >= NFFT * NFREQ) return;
  int n = idx / NFREQ, k = idx - n * NFREQ;
  int ph = (n * k) % NFFT;
  double ang = (double)ph * (TWO_PI_D / 800.0);
  Tc[idx] = cos(ang);
  Ts[idx] = -sin(ang);
}

// ---------------- InverseMelScale: 50 SGD iterations in-kernel ----------------
__global__ __launch_bounds__(128) void k_sgd(
    const float* __restrict__ spec0, const float* __restrict__ xmel,
    const float* __restrict__ fbT, const int* __restrict__ mlo,
    const int* __restrict__ mhi, const int* __restrict__ fm0,
    const float* __restrict__ fw0, const float* __restrict__ fw1,
    float* __restrict__ mag) {
  __shared__ float s_spec[NFREQ], s_vel[NFREQ], s_diff[NMELS], s_mel[NMELS];
  const int row = blockIdx.x;
  const int b = row / TT, t = row - b * TT;
  const int tid = threadIdx.x;
  for (int f = tid; f < NFREQ; f += 128) { s_spec[f] = spec0[row * NFREQ + f]; s_vel[f] = 0.f; }
  if (tid < NMELS) s_mel[tid] = xmel[(b * NMELS + tid) * TT + t];
  __syncthreads();
  for (int it = 0; it < SGDITERS; ++it) {
    if (tid < NMELS) {
      float acc = 0.f;
      const int lo = mlo[tid], hi = mhi[tid];
      const float* fr = fbT + tid * NFREQ;
      for (int f = lo; f < hi; ++f) acc = fmaf(s_spec[f], fr[f], acc);
      s_diff[tid] = s_mel[tid] - acc;
    }
    __syncthreads();
    for (int f = tid; f < NFREQ; f += 128) {
      int m0 = fm0[f];
      int m1 = m0 + 1; if (m1 > NMELS - 1) m1 = NMELS - 1;
      float d = s_diff[m0] * fw0[f] + s_diff[m1] * fw1[f];
      float g = -SGD_SCALE * d;
      float v = 0.9f * s_vel[f] + g;
      s_vel[f] = v;
      float sp = s_spec[f] - 0.1f * v;
      s_spec[f] = sp > 0.f ? sp : 0.f;
    }
    __syncthreads();
  }
  for (int f = tid; f < NFREQ; f += 128) mag[row * NFREQ + f] = sqrtf(s_spec[f]);
}

// ---------------- GEMM-DFT kernels (fp64 accumulate) ----------------
#define BM 64
#define BN 64
#define BK 16

// frames(4096x800) = [mag*ar | mag*ai](4096x802) @ [Cc ; Cs](802x800)
__global__ __launch_bounds__(256) void k_irfft(
    const float* __restrict__ mag, const float* __restrict__ ar,
    const float* __restrict__ ai, const double* __restrict__ Cc,
    const double* __restrict__ Cs, float* __restrict__ frames) {
  __shared__ double As[BK][BM];
  __shared__ double Bs[BK][BN];
  const int tid = threadIdx.x;
  const int row0 = blockIdx.y * BM;
  const int col0 = blockIdx.x * BN;
  const int tm0 = (tid >> 4) * 4, tn0 = (tid & 15) * 4;
  const int am = tid >> 2, ak0 = (tid & 3) * 4;
  const int bk = tid >> 4, bn0 = (tid & 15) * 4;
  double acc[4][4] = {};
  const int grow = row0 + am;
  for (int k0 = 0; k0 < 802; k0 += BK) {
#pragma unroll
    for (int q = 0; q < 4; ++q) {
      int kk = k0 + ak0 + q;
      double v = 0.0;
      if (kk < 802) {
        int k = (kk < NFREQ) ? kk : kk - NFREQ;
        int gi = grow * NFREQ + k;
        float aa = (kk < NFREQ) ? ar[gi] : ai[gi];
        v = (double)mag[gi] * (double)aa;   // exact fp64 product of fp32 data
      }
      As[ak0 + q][am] = v;
    }
    {
      int kk = k0 + bk;
#pragma unroll
      for (int q = 0; q < 4; ++q) {
        int n = col0 + bn0 + q;
        double v = 0.0;
        if (kk < 802 && n < NFFT)
          v = (kk < NFREQ) ? Cc[kk * NFFT + n] : Cs[(kk - NFREQ) * NFFT + n];
        Bs[bk][bn0 + q] = v;
      }
    }
    __syncthreads();
#pragma unroll
    for (int kk = 0; kk < BK; ++kk) {
      double av[4], bv[4];
#pragma unroll
      for (int i = 0; i < 4; ++i) av[i] = As[kk][tm0 + i];
#pragma unroll
      for (int j = 0; j < 4; ++j) bv[j] = Bs[kk][tn0 + j];
#pragma unroll
      for (int i = 0; i < 4; ++i)
#pragma unroll
        for (int j = 0; j < 4; ++j)
          acc[i][j] = fma(av[i], bv[j], acc[i][j]);
    }
    __syncthreads();
  }
#pragma unroll
  for (int i = 0; i < 4; ++i) {
    int row = row0 + tm0 + i;
#pragma unroll
    for (int j = 0; j < 4; ++j) {
      int col = col0 + tn0 + j;
      if (col < NFFT) frames[row * NFFT + col] = (float)acc[i][j];
    }
  }
}

// overlap-add + /wsq : y(8x103000)
__global__ void k_ola(const float* __restrict__ frames, const float* __restrict__ wsq,
                      float* __restrict__ y) {
  int idx = blockIdx.x * blockDim.x + threadIdx.x;
  if (idx >= NB * LY) return;
  int b = idx / LY, j = idx - b * LY;
  int t1 = j / HOPSZ; if (t1 > TT - 1) t1 = TT - 1;
  int t0 = (j - (NFFT - HOPSZ)) / HOPSZ; if (t0 < 0) t0 = 0;
  const float* fb_ = frames + (size_t)b * TT * NFFT;
  float s = 0.f;
  for (int t = t0; t <= t1; ++t) s += fb_[t * NFFT + (j - t * HOPSZ)];
  y[idx] = s / wsq[j];
}

// rfft of reflect-padded y, fused momentum + phase-normalize epilogue
__global__ __launch_bounds__(256) void k_rfft_update(
    const float* __restrict__ y, const double* __restrict__ wind,
    const double* __restrict__ Tc, const double* __restrict__ Ts,
    float* __restrict__ ar, float* __restrict__ ai,
    float* __restrict__ tpr, float* __restrict__ tpi, float beta) {
  __shared__ double As[BK][BM];
  __shared__ double Bct[BK][BN];
  __shared__ double Bst[BK][BN];
  const int tid = threadIdx.x;
  const int row0 = blockIdx.y * BM;
  const int col0 = blockIdx.x * BN;
  const int tm0 = (tid >> 4) * 4, tn0 = (tid & 15) * 4;
  const int am = tid >> 2, ak0 = (tid & 3) * 4;
  const int bk = tid >> 4, bn0 = (tid & 15) * 4;
  double accr[4][4] = {}, acci[4][4] = {};
  const int grow = row0 + am;
  const int bidx = grow >> 9;
  const int tfr = grow & 511;
  const int start = tfr * HOPSZ;
  const float* yb = y + (size_t)bidx * LY;
  for (int k0 = 0; k0 < NFFT; k0 += BK) {
#pragma unroll
    for (int q = 0; q < 4; ++q) {
      int kk = k0 + ak0 + q;
      int j = start + kk;
      // reflect-pad mapping into untrimmed y
      int jm = (j < PADW) ? (NFFT - j) : ((j < PADW + LOUTW) ? j : (205198 - j));
      As[ak0 + q][am] = (double)yb[jm] * wind[kk];   // exact fp64 product
    }
    {
      int kk = k0 + bk;
#pragma unroll
      for (int q = 0; q < 4; ++q) {
        int n = col0 + bn0 + q;
        double vc = 0.0, vs = 0.0;
        if (n < NFREQ) { vc = Tc[kk * NFREQ + n]; vs = Ts[kk * NFREQ + n]; }
        Bct[bk][bn0 + q] = vc;
        Bst[bk][bn0 + q] = vs;
      }
    }
    __syncthreads();
#pragma unroll
    for (int kk = 0; kk < BK; ++kk) {
      double av[4], cv[4], sv[4];
#pragma unroll
      for (int i = 0; i < 4; ++i) av[i] = As[kk][tm0 + i];
#pragma unroll
      for (int j = 0; j < 4; ++j) { cv[j] = Bct[kk][tn0 + j]; sv[j] = Bst[kk][tn0 + j]; }
#pragma unroll
      for (int i = 0; i < 4; ++i)
#pragma unroll
        for (int jj = 0; jj < 4; ++jj) {
          accr[i][jj] = fma(av[i], cv[jj], accr[i][jj]);
          acci[i][jj] = fma(av[i], sv[jj], acci[i][jj]);
        }
    }
    __syncthreads();
  }
#pragma unroll
  for (int i = 0; i < 4; ++i) {
    int row = row0 + tm0 + i;
#pragma unroll
    for (int jj = 0; jj < 4; ++jj) {
      int col = col0 + tn0 + jj;
      if (col < NFREQ) {
        int idx = row * NFREQ + col;
        float rr = (float)accr[i][jj], ri = (float)acci[i][jj];  // fp32 "rebuilt" like jax
        float nr = rr - beta * tpr[idx];
        float ni = ri - beta * tpi[idx];
        tpr[idx] = rr; tpi[idx] = ri;
        float den = sqrtf(nr * nr + ni * ni) + 1e-16f;
        ar[idx] = nr / den;
        ai[idx] = ni / den;
      }
    }
  }
}

// ---------------- epilogue: peak-normalize ----------------
__global__ void k_absmax(const float* __restrict__ y, float* __restrict__ peak) {
  __shared__ float red[256];
  int b = blockIdx.x;
  const float* yb = y + (size_t)b * LY + PADW;
  float mx = 0.f;
  for (int j = threadIdx.x; j < LOUTW; j += 256) mx = fmaxf(mx, fabsf(yb[j]));
  red[threadIdx.x] = mx;
  __syncthreads();
  for (int s2 = 128; s2 > 0; s2 >>= 1) {
    if (threadIdx.x < s2) red[threadIdx.x] = fmaxf(red[threadIdx.x], red[threadIdx.x + s2]);
    __syncthreads();
  }
  if (threadIdx.x == 0) peak[b] = red[0];
}

__global__ void k_scale(const float* __restrict__ y, const float* __restrict__ peak,
                        float* __restrict__ out, float target) {
  int idx = blockIdx.x * blockDim.x + threadIdx.x;
  if (idx >= NB * LOUTW) return;
  int b = idx / LOUTW, j = idx - b * LOUTW;
  out[idx] = y[(size_t)b * LY + PADW + j] * (target / peak[b]);
}

__global__ void k_zero2(float* __restrict__ a, float* __restrict__ b, int n) {
  int i = blockIdx.x * blockDim.x + threadIdx.x;
  if (i < n) { a[i] = 0.f; b[i] = 0.f; }
}

// ---------------- host ----------------
extern "C" void kernel_launch(void* const* d_in, const int* in_sizes, int n_in,
                              void* d_out, int out_size, void* d_ws, size_t ws_size,
                              hipStream_t stream) {
  const float* xmel = (const float*)d_in[0];   // (8, 80, 512) f32
  float* out = (float*)d_out;                  // (8, 1, 102200) f32

  char* p = (char*)d_ws;
  auto alloc = [&](size_t nbytes) -> void* {
    void* r = (void*)p;
    p += (nbytes + 255) & ~(size_t)255;
    return r;
  };
  float* mag  = (float*)alloc((size_t)NSPEC * 4);
  float* ar   = (float*)alloc((size_t)NSPEC * 4);
  float* ai   = (float*)alloc((size_t)NSPEC * 4);
  float* tpr  = (float*)alloc((size_t)NSPEC * 4);
  float* tpi  = (float*)alloc((size_t)NSPEC * 4);
  float* y    = (float*)alloc((size_t)NB * LY * 4);
  double* Cc  = (double*)alloc((size_t)NFREQ * NFFT * 8);
  double* Cs  = (double*)alloc((size_t)NFREQ * NFFT * 8);
  double* Tc  = (double*)alloc((size_t)NFFT * NFREQ * 8);
  double* Ts  = (double*)alloc((size_t)NFFT * NFREQ * 8);
  float* win  = (float*)alloc(NFFT * 4);
  double* wind= (double*)alloc(NFFT * 8);
  float* wsq  = (float*)alloc((size_t)LY * 4);
  float* fbT  = (float*)alloc((size_t)NMELS * NFREQ * 4);
  float* fw0  = (float*)alloc(NFREQ * 4);
  float* fw1  = (float*)alloc(NFREQ * 4);
  float* peak = (float*)alloc(NB * 4);
  int* fm0    = (int*)alloc(NFREQ * 4);
  int* mlo    = (int*)alloc(NMELS * 4);
  int* mhi    = (int*)alloc(NMELS * 4);
  float* frames = (float*)alloc((size_t)NROWS * NFFT * 4);
  float* spec0 = frames;  // alias: spec0 consumed by k_sgd before frames are written

  if ((size_t)(p - (char*)d_ws) > ws_size) return;  // insufficient scratch: fail loudly

  // derived threefry keys (host-side, deterministic)
  unsigned k1a, k1b, k2a, k2b, kra, krb, kia, kib;
#if PRNG_PARTITIONABLE
  {
    unsigned o0, o1;
    tf2x32(0u, 1u, 0u, 0u, o0, o1); k1a = o0; k1b = o1;
    tf2x32(0u, 1u, 0u, 1u, o0, o1); k2a = o0; k2b = o1;
    tf2x32(k2a, k2b, 0u, 0u, o0, o1); kra = o0; krb = o1;
    tf2x32(k2a, k2b, 0u, 1u, o0, o1); kia = o0; kib = o1;
  }
#else
  {
    unsigned a0, a1, b0, b1;
    tf2x32(0u, 1u, 0u, 2u, a0, a1); tf2x32(0u, 1u, 1u, 3u, b0, b1);
    k1a = a0; k1b = b0; k2a = a1; k2b = b1;
    tf2x32(k2a, k2b, 0u, 2u, a0, a1); tf2x32(k2a, k2b, 1u, 3u, b0, b1);
    kra = a0; krb = b0; kia = a1; kib = b1;
  }
#endif

  // init
  k_fb<<<2, 256, 0, stream>>>(fbT, fm0, fw0, fw1);
  k_ranges<<<1, 128, 0, stream>>>(fbT, mlo, mhi);
  k_wsq<<<(LY + 255) / 256, 256, 0, stream>>>(wsq, win, wind);
  k_tab_ir<<<(NFREQ * NFFT + 255) / 256, 256, 0, stream>>>(Cc, Cs);
  k_tab_r<<<(NFFT * NFREQ + 255) / 256, 256, 0, stream>>>(Tc, Ts);
  k_zero2<<<(NSPEC + 255) / 256, 256, 0, stream>>>(tpr, tpi, NSPEC);
#if PRNG_PARTITIONABLE
  k_rand_spec<<<(NSPEC + 255) / 256, 256, 0, stream>>>(k1a, k1b, spec0);
  k_rand_ang<<<(NSPEC + 255) / 256, 256, 0, stream>>>(kra, krb, kia, kib, ar, ai);
#else
  k_rand_spec<<<(HALFN + 255) / 256, 256, 0, stream>>>(k1a, k1b, spec0);
  k_rand_ang<<<(HALFN + 255) / 256, 256, 0, stream>>>(kra, krb, kia, kib, ar, ai);
#endif

  // InverseMelScale (50 SGD iters, per-row independent)
  k_sgd<<<NROWS, 128, 0, stream>>>(spec0, xmel, fbT, mlo, mhi, fm0, fw0, fw1, mag);

  // Griffin-Lim
  const float beta = (float)(0.99 / 1.99);
  for (int it = 0; it < GLITERS; ++it) {
    k_irfft<<<dim3(13, 64), 256, 0, stream>>>(mag, ar, ai, Cc, Cs, frames);
    k_ola<<<(NB * LY + 255) / 256, 256, 0, stream>>>(frames, wsq, y);
    k_rfft_update<<<dim3(7, 64), 256, 0, stream>>>(y, wind, Tc, Ts, ar, ai, tpr, tpi, beta);
  }
  k_irfft<<<dim3(13, 64), 256, 0, stream>>>(mag, ar, ai, Cc, Cs, frames);
  k_ola<<<(NB * LY + 255) / 256, 256, 0, stream>>>(frames, wsq, y);

  // normalize
  k_absmax<<<NB, 256, 0, stream>>>(y, peak);
  const float target = (float)pow(10.0, -0.1 / 20.0);
  k_scale<<<(NB * LOUTW + 255) / 256, 256, 0, stream>>>(y, peak, out, target);
}

// Round 5
// 4264.845 us; speedup vs baseline: 3.5382x; 3.5382x over previous
//
#include <hip/hip_runtime.h>
#include <math.h>

// ---------------- problem constants ----------------
#define NB 8
#define NMELS 80
#define TT 512
#define NFREQ 401
#define NFFT 800
#define HOPSZ 200
#define NROWS (NB*TT)          // 4096 frames
#define LY 103000              // untrimmed istft length
#define LOUTW 102200
#define PADW 400
#define NSPEC (NROWS*NFREQ)    // 1640448
#define GLITERS 30
#define SGDITERS 50
#define SGD_SCALE 0.003125f    // 2/(B*n_mels)
#define K1P 832                // irfft GEMM K padded (26*32)
#define K2 800                 // rfft GEMM K (25*32)
#define N1P 896                // irfft GEMM N padded (7*128)
#define N2P 512                // rfft GEMM N padded (4*128)
// scales: A x256, B1 x(800*16) [/800 dropped + 16], lo parts x2048
#define WSQ_SCALE 3276800.0f   // 800*16*256
#define LO_INV 4.8828125e-4f   // 2^-11

#define TWO_PI_D 6.283185307179586476925286766559

typedef _Float16 half8 __attribute__((ext_vector_type(8)));
typedef float f32x4 __attribute__((ext_vector_type(4)));

// ---------------- threefry2x32 (20 rounds) ----------------
__host__ __device__ inline void tf2x32(unsigned k0, unsigned k1,
                                       unsigned x0, unsigned x1,
                                       unsigned& o0, unsigned& o1) {
  unsigned ks0 = k0, ks1 = k1, ks2 = k0 ^ k1 ^ 0x1BD11BDAu;
  x0 += ks0; x1 += ks1;
#define TF_R(r) { x0 += x1; x1 = (x1 << (r)) | (x1 >> (32 - (r))); x1 ^= x0; }
  TF_R(13) TF_R(15) TF_R(26) TF_R(6)
  x0 += ks1; x1 += ks2 + 1u;
  TF_R(17) TF_R(29) TF_R(16) TF_R(24)
  x0 += ks2; x1 += ks0 + 2u;
  TF_R(13) TF_R(15) TF_R(26) TF_R(6)
  x0 += ks0; x1 += ks1 + 3u;
  TF_R(17) TF_R(29) TF_R(16) TF_R(24)
  x0 += ks1; x1 += ks2 + 4u;
  TF_R(13) TF_R(15) TF_R(26) TF_R(6)
  x0 += ks2; x1 += ks0 + 5u;
#undef TF_R
  o0 = x0; o1 = x1;
}

__device__ inline float u01(unsigned bits) {
  unsigned u = (bits >> 9) | 0x3f800000u;
  return __uint_as_float(u) - 1.0f;
}

__device__ inline int ang_map(int g) {
  int b = g / (NFREQ * TT);
  int r = g - b * (NFREQ * TT);
  int f = r / TT;
  int t = r - f * TT;
  return (b * TT + t) * NFREQ + f;
}

__global__ void k_rand_spec(unsigned ka, unsigned kb, float* __restrict__ spec) {
  int i = blockIdx.x * blockDim.x + threadIdx.x;
  if (i >= NSPEC) return;
  unsigned o0, o1; tf2x32(ka, kb, 0u, (unsigned)i, o0, o1);
  spec[i] = u01(o0 ^ o1);    // partitionable 32-bit fold
}

__global__ void k_rand_ang(unsigned kra, unsigned krb, unsigned kia, unsigned kib,
                           float* __restrict__ ar, float* __restrict__ ai) {
  int g = blockIdx.x * blockDim.x + threadIdx.x;
  if (g >= NSPEC) return;
  int d = ang_map(g);
  unsigned o0, o1;
  tf2x32(kra, krb, 0u, (unsigned)g, o0, o1); ar[d] = u01(o0 ^ o1);
  tf2x32(kia, kib, 0u, (unsigned)g, o0, o1); ai[d] = u01(o0 ^ o1);
}

// ---------------- mel filterbank ----------------
__device__ inline double mel2hz_d(double mel) {
  return 700.0 * (pow(10.0, mel / 2595.0) - 1.0);
}

__global__ void k_fb(float* __restrict__ fbT, int* __restrict__ fm0,
                     float* __restrict__ fw0, float* __restrict__ fw1) {
  int f = blockIdx.x * blockDim.x + threadIdx.x;
  if (f >= NFREQ) return;
  const double freq = 10.0 * (double)f;
  const double melmax = 2595.0 * log10(1.0 + 4000.0 / 700.0);
  const double step = melmax / 81.0;
  int first = -1; float w0v = 0.f, w1v = 0.f;
  double p0 = 0.0;
  double p1 = mel2hz_d(step);
  for (int m = 0; m < NMELS; ++m) {
    double m2 = (m + 2 == 81) ? melmax : (double)(m + 2) * step;
    double p2 = mel2hz_d(m2);
    double down = (freq - p0) / (p1 - p0);
    double up   = (p2 - freq) / (p2 - p1);
    double v = down < up ? down : up;
    if (v < 0.0) v = 0.0;
    float vf = (float)v;
    fbT[m * NFREQ + f] = vf;
    if (vf > 0.f) {
      if (first < 0) { first = m; w0v = vf; }
      else if (m == first + 1) { w1v = vf; }
    }
    p0 = p1; p1 = p2;
  }
  fm0[f] = first < 0 ? 0 : first;
  fw0[f] = first < 0 ? 0.f : w0v;
  fw1[f] = w1v;
}

__global__ void k_ranges(const float* __restrict__ fbT, int* __restrict__ mlo,
                         int* __restrict__ mhi) {
  int m = threadIdx.x;
  if (m >= NMELS) return;
  int lo = NFREQ, hi = 0;
  for (int f = 0; f < NFREQ; ++f)
    if (fbT[m * NFREQ + f] > 0.f) { if (lo == NFREQ) lo = f; hi = f + 1; }
  mlo[m] = lo; mhi[m] = hi < lo ? lo : hi;
}

// ---------------- window + OLA weight (pre-scaled) ----------------
__device__ inline double hann_d(int i) {
  return 0.5 - 0.5 * cos(TWO_PI_D * (double)i / 800.0);
}

__global__ void k_wsq(float* __restrict__ wsqs, float* __restrict__ win) {
  int j = blockIdx.x * blockDim.x + threadIdx.x;
  if (j >= LY) return;
  if (j < NFFT) win[j] = (float)hann_d(j);
  int t1 = j / HOPSZ; if (t1 > TT - 1) t1 = TT - 1;
  int t0 = (j - (NFFT - HOPSZ)) / HOPSZ; if (t0 < 0) t0 = 0;
  float s = 0.f;
  for (int t = t0; t <= t1; ++t) {
    float w = (float)hann_d(j - t * HOPSZ);
    s += w * w;
  }
  wsqs[j] = WSQ_SCALE * fmaxf(s, 1e-11f);
}

// ---------------- f16-split DFT tables ----------------
// B1 (irfft, transposed [n=time 0..895][kk=freq-row 0..831]), scaled x16 (and
// the reference /800 dropped): kk<401: re-row, 401..801: im-row, rest zero.
__global__ void k_tabs1(_Float16* __restrict__ Bh, _Float16* __restrict__ Bl) {
  int idx = blockIdx.x * blockDim.x + threadIdx.x;
  if (idx >= N1P * K1P) return;
  int n = idx / K1P, kk = idx - n * K1P;
  double v = 0.0;
  if (n < NFFT && kk < 802) {
    double wn = hann_d(n);
    if (kk < NFREQ) {
      int k = kk;
      double ak = (k == 0 || k == 400) ? 1.0 : 2.0;
      int ph = (k * n) % NFFT;
      v = 16.0 * ak * cos((double)ph * (TWO_PI_D / 800.0)) * wn;
    } else {
      int k = kk - NFREQ;
      if (k != 0 && k != 400) {
        int ph = (k * n) % NFFT;
        v = 16.0 * (-2.0) * sin((double)ph * (TWO_PI_D / 800.0)) * wn;
      }
    }
  }
  float vf = (float)v;
  _Float16 h = (_Float16)vf;
  Bh[idx] = h;
  Bl[idx] = (_Float16)((vf - (float)h) * 2048.0f);
}

// B2 (rfft, transposed [n=freq-col 0..511][k=time 0..799]): cos and -sin
__global__ void k_tabs2(_Float16* __restrict__ Bch, _Float16* __restrict__ Bcl,
                        _Float16* __restrict__ Bsh, _Float16* __restrict__ Bsl) {
  int idx = blockIdx.x * blockDim.x + threadIdx.x;
  if (idx >= N2P * K2) return;
  int n = idx / K2, k = idx - n * K2;
  double c = 0.0, s = 0.0;
  if (n < NFREQ) {
    int ph = (n * k) % NFFT;
    double ang = (double)ph * (TWO_PI_D / 800.0);
    c = cos(ang); s = -sin(ang);
  }
  float cf = (float)c, sf = (float)s;
  _Float16 ch = (_Float16)cf, sh = (_Float16)sf;
  Bch[idx] = ch; Bcl[idx] = (_Float16)((cf - (float)ch) * 2048.0f);
  Bsh[idx] = sh; Bsl[idx] = (_Float16)((sf - (float)sh) * 2048.0f);
}

// ---------------- InverseMelScale: 50 SGD iterations in-kernel ----------------
__global__ __launch_bounds__(128) void k_sgd(
    const float* __restrict__ spec0, const float* __restrict__ xmel,
    const float* __restrict__ fbT, const int* __restrict__ mlo,
    const int* __restrict__ mhi, const int* __restrict__ fm0,
    const float* __restrict__ fw0, const float* __restrict__ fw1,
    float* __restrict__ mag) {
  __shared__ float s_spec[NFREQ], s_vel[NFREQ], s_diff[NMELS], s_mel[NMELS];
  const int row = blockIdx.x;
  const int b = row / TT, t = row - b * TT;
  const int tid = threadIdx.x;
  for (int f = tid; f < NFREQ; f += 128) { s_spec[f] = spec0[row * NFREQ + f]; s_vel[f] = 0.f; }
  if (tid < NMELS) s_mel[tid] = xmel[(b * NMELS + tid) * TT + t];
  __syncthreads();
  for (int it = 0; it < SGDITERS; ++it) {
    if (tid < NMELS) {
      float acc = 0.f;
      const int lo = mlo[tid], hi = mhi[tid];
      const float* fr = fbT + tid * NFREQ;
      for (int f = lo; f < hi; ++f) acc = fmaf(s_spec[f], fr[f], acc);
      s_diff[tid] = s_mel[tid] - acc;
    }
    __syncthreads();
    for (int f = tid; f < NFREQ; f += 128) {
      int m0 = fm0[f];
      int m1 = m0 + 1; if (m1 > NMELS - 1) m1 = NMELS - 1;
      float d = s_diff[m0] * fw0[f] + s_diff[m1] * fw1[f];
      float g = -SGD_SCALE * d;
      float v = 0.9f * s_vel[f] + g;
      s_vel[f] = v;
      float sp = s_spec[f] - 0.1f * v;
      s_spec[f] = sp > 0.f ? sp : 0.f;
    }
    __syncthreads();
  }
  for (int f = tid; f < NFREQ; f += 128) mag[row * NFREQ + f] = sqrtf(s_spec[f]);
}

// ---------------- A-matrix prep (fp32 -> f16 hi/lo, x256) ----------------
__global__ void k_prep1(const float* __restrict__ mag, const float* __restrict__ ar,
                        const float* __restrict__ ai,
                        _Float16* __restrict__ Ah, _Float16* __restrict__ Al) {
  int kk = blockIdx.x * 256 + threadIdx.x;
  if (kk >= K1P) return;
  int row = blockIdx.y;
  float v = 0.f;
  if (kk < 802) {
    int k = (kk < NFREQ) ? kk : kk - NFREQ;
    int gi = row * NFREQ + k;
    float aa = (kk < NFREQ) ? ar[gi] : ai[gi];
    v = mag[gi] * aa * 256.0f;
  }
  _Float16 h = (_Float16)v;
  size_t o = (size_t)row * K1P + kk;
  Ah[o] = h;
  Al[o] = (_Float16)((v - (float)h) * 2048.0f);
}

__global__ void k_prep2(const float* __restrict__ y, const float* __restrict__ win,
                        _Float16* __restrict__ Ah, _Float16* __restrict__ Al) {
  int kk = blockIdx.x * 256 + threadIdx.x;
  if (kk >= K2) return;
  int row = blockIdx.y;
  int b = row >> 9, tt = row & 511;
  int j = tt * HOPSZ + kk;
  int jm = (j < PADW) ? (NFFT - j) : ((j < PADW + LOUTW) ? j : (205198 - j));
  float v = y[(size_t)b * LY + jm] * win[kk] * 256.0f;
  _Float16 h = (_Float16)v;
  size_t o = (size_t)row * K2 + kk;
  Ah[o] = h;
  Al[o] = (_Float16)((v - (float)h) * 2048.0f);
}

// ---------------- MFMA split-f16 GEMM 1: frames = A1 @ B1 ----------------
// C(4096 x 800) ; block tile 64(M) x 128(N), 4 waves each 32x64
__global__ __launch_bounds__(256) void k_mm1(
    const _Float16* __restrict__ Ah, const _Float16* __restrict__ Al,
    const _Float16* __restrict__ Bh, const _Float16* __restrict__ Bl,
    float* __restrict__ frames) {
  __shared__ __align__(16) _Float16 As_h[64 * 40], As_l[64 * 40];
  __shared__ __align__(16) _Float16 Bs_h[128 * 40], Bs_l[128 * 40];
  const int t = threadIdx.x;
  const int row0 = blockIdx.y * 64;
  const int col0 = blockIdx.x * 128;
  const int ar_ = t >> 2, ak_ = (t & 3) * 8;
  const int br_ = t >> 1, bk_ = (t & 1) * 16;
  const int lane = t & 63, wv = t >> 6;
  const int wm = wv & 1, wn = wv >> 1;
  const int lm = lane & 15, qd = lane >> 4;
  f32x4 acc0[2][4] = {}, acc1[2][4] = {};
  const size_t abase = (size_t)(row0 + ar_) * K1P;
  const size_t bbase = (size_t)(col0 + br_) * K1P;
  for (int k0 = 0; k0 < K1P; k0 += 32) {
    *(uint4*)&As_h[ar_ * 40 + ak_] = *(const uint4*)&Ah[abase + k0 + ak_];
    *(uint4*)&As_l[ar_ * 40 + ak_] = *(const uint4*)&Al[abase + k0 + ak_];
    *(uint4*)&Bs_h[br_ * 40 + bk_]     = *(const uint4*)&Bh[bbase + k0 + bk_];
    *(uint4*)&Bs_h[br_ * 40 + bk_ + 8] = *(const uint4*)&Bh[bbase + k0 + bk_ + 8];
    *(uint4*)&Bs_l[br_ * 40 + bk_]     = *(const uint4*)&Bl[bbase + k0 + bk_];
    *(uint4*)&Bs_l[br_ * 40 + bk_ + 8] = *(const uint4*)&Bl[bbase + k0 + bk_ + 8];
    __syncthreads();
    half8 a_h[2], a_l[2];
#pragma unroll
    for (int i = 0; i < 2; ++i) {
      int m = wm * 32 + i * 16 + lm;
      a_h[i] = *(const half8*)&As_h[m * 40 + qd * 8];
      a_l[i] = *(const half8*)&As_l[m * 40 + qd * 8];
    }
#pragma unroll
    for (int j = 0; j < 4; ++j) {
      int n = wn * 64 + j * 16 + lm;
      half8 b_h = *(const half8*)&Bs_h[n * 40 + qd * 8];
      half8 b_l = *(const half8*)&Bs_l[n * 40 + qd * 8];
#pragma unroll
      for (int i = 0; i < 2; ++i) {
        acc0[i][j] = __builtin_amdgcn_mfma_f32_16x16x32_f16(a_h[i], b_h, acc0[i][j], 0, 0, 0);
        acc1[i][j] = __builtin_amdgcn_mfma_f32_16x16x32_f16(a_h[i], b_l, acc1[i][j], 0, 0, 0);
        acc1[i][j] = __builtin_amdgcn_mfma_f32_16x16x32_f16(a_l[i], b_h, acc1[i][j], 0, 0, 0);
      }
    }
    __syncthreads();
  }
#pragma unroll
  for (int j = 0; j < 4; ++j) {
    int col = col0 + wn * 64 + j * 16 + lm;
    if (col < NFFT) {
#pragma unroll
      for (int i = 0; i < 2; ++i)
#pragma unroll
        for (int r = 0; r < 4; ++r) {
          int row = row0 + wm * 32 + i * 16 + qd * 4 + r;
          frames[(size_t)row * NFFT + col] = acc0[i][j][r] + acc1[i][j][r] * LO_INV;
        }
    }
  }
}

// ---------------- overlap-add + /wsq ----------------
__global__ void k_ola(const float* __restrict__ frames, const float* __restrict__ wsqs,
                      float* __restrict__ y) {
  int idx = blockIdx.x * blockDim.x + threadIdx.x;
  if (idx >= NB * LY) return;
  int b = idx / LY, j = idx - b * LY;
  int t1 = j / HOPSZ; if (t1 > TT - 1) t1 = TT - 1;
  int t0 = (j - (NFFT - HOPSZ)) / HOPSZ; if (t0 < 0) t0 = 0;
  const float* fb_ = frames + (size_t)b * TT * NFFT;
  float s = 0.f;
  for (int t = t0; t <= t1; ++t) s += fb_[t * NFFT + (j - t * HOPSZ)];
  y[idx] = s / wsqs[j];
}

// ---------------- MFMA split-f16 GEMM 2: rfft + momentum + normalize ----------------
__global__ __launch_bounds__(256) void k_mm2(
    const _Float16* __restrict__ Ah, const _Float16* __restrict__ Al,
    const _Float16* __restrict__ Bch, const _Float16* __restrict__ Bcl,
    const _Float16* __restrict__ Bsh, const _Float16* __restrict__ Bsl,
    float* __restrict__ arp, float* __restrict__ aip,
    float* __restrict__ tppr, float* __restrict__ tppi, float beta) {
  __shared__ __align__(16) _Float16 As_h[64 * 40], As_l[64 * 40];
  __shared__ __align__(16) _Float16 Bc_h[128 * 40], Bc_l[128 * 40];
  __shared__ __align__(16) _Float16 Bn_h[128 * 40], Bn_l[128 * 40];
  const int t = threadIdx.x;
  const int row0 = blockIdx.y * 64;
  const int col0 = blockIdx.x * 128;
  const int ar_ = t >> 2, ak_ = (t & 3) * 8;
  const int br_ = t >> 1, bk_ = (t & 1) * 16;
  const int lane = t & 63, wv = t >> 6;
  const int wm = wv & 1, wn = wv >> 1;
  const int lm = lane & 15, qd = lane >> 4;
  f32x4 cr0[2][4] = {}, cr1[2][4] = {}, ci0[2][4] = {}, ci1[2][4] = {};
  const size_t abase = (size_t)(row0 + ar_) * K2;
  const size_t bbase = (size_t)(col0 + br_) * K2;
  for (int k0 = 0; k0 < K2; k0 += 32) {
    *(uint4*)&As_h[ar_ * 40 + ak_] = *(const uint4*)&Ah[abase + k0 + ak_];
    *(uint4*)&As_l[ar_ * 40 + ak_] = *(const uint4*)&Al[abase + k0 + ak_];
    *(uint4*)&Bc_h[br_ * 40 + bk_]     = *(const uint4*)&Bch[bbase + k0 + bk_];
    *(uint4*)&Bc_h[br_ * 40 + bk_ + 8] = *(const uint4*)&Bch[bbase + k0 + bk_ + 8];
    *(uint4*)&Bc_l[br_ * 40 + bk_]     = *(const uint4*)&Bcl[bbase + k0 + bk_];
    *(uint4*)&Bc_l[br_ * 40 + bk_ + 8] = *(const uint4*)&Bcl[bbase + k0 + bk_ + 8];
    *(uint4*)&Bn_h[br_ * 40 + bk_]     = *(const uint4*)&Bsh[bbase + k0 + bk_];
    *(uint4*)&Bn_h[br_ * 40 + bk_ + 8] = *(const uint4*)&Bsh[bbase + k0 + bk_ + 8];
    *(uint4*)&Bn_l[br_ * 40 + bk_]     = *(const uint4*)&Bsl[bbase + k0 + bk_];
    *(uint4*)&Bn_l[br_ * 40 + bk_ + 8] = *(const uint4*)&Bsl[bbase + k0 + bk_ + 8];
    __syncthreads();
    half8 a_h[2], a_l[2];
#pragma unroll
    for (int i = 0; i < 2; ++i) {
      int m = wm * 32 + i * 16 + lm;
      a_h[i] = *(const half8*)&As_h[m * 40 + qd * 8];
      a_l[i] = *(const half8*)&As_l[m * 40 + qd * 8];
    }
#pragma unroll
    for (int j = 0; j < 4; ++j) {
      int n = wn * 64 + j * 16 + lm;
      half8 bc_h = *(const half8*)&Bc_h[n * 40 + qd * 8];
      half8 bc_l = *(const half8*)&Bc_l[n * 40 + qd * 8];
      half8 bs_h = *(const half8*)&Bn_h[n * 40 + qd * 8];
      half8 bs_l = *(const half8*)&Bn_l[n * 40 + qd * 8];
#pragma unroll
      for (int i = 0; i < 2; ++i) {
        cr0[i][j] = __builtin_amdgcn_mfma_f32_16x16x32_f16(a_h[i], bc_h, cr0[i][j], 0, 0, 0);
        cr1[i][j] = __builtin_amdgcn_mfma_f32_16x16x32_f16(a_h[i], bc_l, cr1[i][j], 0, 0, 0);
        cr1[i][j] = __builtin_amdgcn_mfma_f32_16x16x32_f16(a_l[i], bc_h, cr1[i][j], 0, 0, 0);
        ci0[i][j] = __builtin_amdgcn_mfma_f32_16x16x32_f16(a_h[i], bs_h, ci0[i][j], 0, 0, 0);
        ci1[i][j] = __builtin_amdgcn_mfma_f32_16x16x32_f16(a_h[i], bs_l, ci1[i][j], 0, 0, 0);
        ci1[i][j] = __builtin_amdgcn_mfma_f32_16x16x32_f16(a_l[i], bs_h, ci1[i][j], 0, 0, 0);
      }
    }
    __syncthreads();
  }
#pragma unroll
  for (int j = 0; j < 4; ++j) {
    int col = col0 + wn * 64 + j * 16 + lm;
    if (col < NFREQ) {
#pragma unroll
      for (int i = 0; i < 2; ++i)
#pragma unroll
        for (int r = 0; r < 4; ++r) {
          int row = row0 + wm * 32 + i * 16 + qd * 4 + r;
          int idx = row * NFREQ + col;
          float rr = cr0[i][j][r] + cr1[i][j][r] * LO_INV;   // (x256-scaled rebuilt)
          float ri = ci0[i][j][r] + ci1[i][j][r] * LO_INV;
          float nr = rr - beta * tppr[idx];
          float ni = ri - beta * tppi[idx];
          tppr[idx] = rr; tppi[idx] = ri;
          float den = sqrtf(nr * nr + ni * ni) + 1e-16f;
          arp[idx] = nr / den;
          aip[idx] = ni / den;
        }
    }
  }
}

// ---------------- epilogue: peak-normalize ----------------
__global__ void k_absmax(const float* __restrict__ y, float* __restrict__ peak) {
  __shared__ float red[256];
  int b = blockIdx.x;
  const float* yb = y + (size_t)b * LY + PADW;
  float mx = 0.f;
  for (int j = threadIdx.x; j < LOUTW; j += 256) mx = fmaxf(mx, fabsf(yb[j]));
  red[threadIdx.x] = mx;
  __syncthreads();
  for (int s2 = 128; s2 > 0; s2 >>= 1) {
    if (threadIdx.x < s2) red[threadIdx.x] = fmaxf(red[threadIdx.x], red[threadIdx.x + s2]);
    __syncthreads();
  }
  if (threadIdx.x == 0) peak[b] = red[0];
}

__global__ void k_scale(const float* __restrict__ y, const float* __restrict__ peak,
                        float* __restrict__ out, float target) {
  int idx = blockIdx.x * blockDim.x + threadIdx.x;
  if (idx >= NB * LOUTW) return;
  int b = idx / LOUTW, j = idx - b * LOUTW;
  out[idx] = y[(size_t)b * LY + PADW + j] * (target / peak[b]);
}

__global__ void k_zero2(float* __restrict__ a, float* __restrict__ b, int n) {
  int i = blockIdx.x * blockDim.x + threadIdx.x;
  if (i < n) { a[i] = 0.f; b[i] = 0.f; }
}

// ---------------- host ----------------
extern "C" void kernel_launch(void* const* d_in, const int* in_sizes, int n_in,
                              void* d_out, int out_size, void* d_ws, size_t ws_size,
                              hipStream_t stream) {
  const float* xmel = (const float*)d_in[0];   // (8, 80, 512) f32
  float* out = (float*)d_out;                  // (8, 1, 102200) f32

  char* p = (char*)d_ws;
  auto alloc = [&](size_t nbytes) -> void* {
    void* r = (void*)p;
    p += (nbytes + 255) & ~(size_t)255;
    return r;
  };
  float* mag  = (float*)alloc((size_t)NSPEC * 4);
  float* ar   = (float*)alloc((size_t)NSPEC * 4);
  float* ai   = (float*)alloc((size_t)NSPEC * 4);
  float* tpr  = (float*)alloc((size_t)NSPEC * 4);
  float* tpi  = (float*)alloc((size_t)NSPEC * 4);
  float* y    = (float*)alloc((size_t)NB * LY * 4);
  float* win  = (float*)alloc(NFFT * 4);
  float* wsqs = (float*)alloc((size_t)LY * 4);
  float* fbT  = (float*)alloc((size_t)NMELS * NFREQ * 4);
  float* fw0  = (float*)alloc(NFREQ * 4);
  float* fw1  = (float*)alloc(NFREQ * 4);
  float* peak = (float*)alloc(NB * 4);
  int* fm0    = (int*)alloc(NFREQ * 4);
  int* mlo    = (int*)alloc(NMELS * 4);
  int* mhi    = (int*)alloc(NMELS * 4);
  float* frames = (float*)alloc((size_t)NROWS * NFFT * 4);
  float* spec0 = frames;  // alias: consumed by k_sgd before frames written
  _Float16* A1h = (_Float16*)alloc((size_t)NROWS * K1P * 2);
  _Float16* A1l = (_Float16*)alloc((size_t)NROWS * K1P * 2);
  _Float16* B1h = (_Float16*)alloc((size_t)N1P * K1P * 2);
  _Float16* B1l = (_Float16*)alloc((size_t)N1P * K1P * 2);
  _Float16* B2ch = (_Float16*)alloc((size_t)N2P * K2 * 2);
  _Float16* B2cl = (_Float16*)alloc((size_t)N2P * K2 * 2);
  _Float16* B2sh = (_Float16*)alloc((size_t)N2P * K2 * 2);
  _Float16* B2sl = (_Float16*)alloc((size_t)N2P * K2 * 2);
  _Float16* A2h = A1h;  // alias: A1 dead once k_mm1 completes
  _Float16* A2l = A1l;

  if ((size_t)(p - (char*)d_ws) > ws_size) return;  // insufficient scratch

  // derived threefry keys (jax partitionable split)
  unsigned k1a, k1b, k2a, k2b, kra, krb, kia, kib;
  {
    unsigned o0, o1;
    tf2x32(0u, 1u, 0u, 0u, o0, o1); k1a = o0; k1b = o1;
    tf2x32(0u, 1u, 0u, 1u, o0, o1); k2a = o0; k2b = o1;
    tf2x32(k2a, k2b, 0u, 0u, o0, o1); kra = o0; krb = o1;
    tf2x32(k2a, k2b, 0u, 1u, o0, o1); kia = o0; kib = o1;
  }

  // init
  k_fb<<<2, 256, 0, stream>>>(fbT, fm0, fw0, fw1);
  k_ranges<<<1, 128, 0, stream>>>(fbT, mlo, mhi);
  k_wsq<<<(LY + 255) / 256, 256, 0, stream>>>(wsqs, win);
  k_tabs1<<<(N1P * K1P + 255) / 256, 256, 0, stream>>>(B1h, B1l);
  k_tabs2<<<(N2P * K2 + 255) / 256, 256, 0, stream>>>(B2ch, B2cl, B2sh, B2sl);
  k_zero2<<<(NSPEC + 255) / 256, 256, 0, stream>>>(tpr, tpi, NSPEC);
  k_rand_spec<<<(NSPEC + 255) / 256, 256, 0, stream>>>(k1a, k1b, spec0);
  k_rand_ang<<<(NSPEC + 255) / 256, 256, 0, stream>>>(kra, krb, kia, kib, ar, ai);

  // InverseMelScale
  k_sgd<<<NROWS, 128, 0, stream>>>(spec0, xmel, fbT, mlo, mhi, fm0, fw0, fw1, mag);

  // Griffin-Lim
  const float beta = (float)(0.99 / 1.99);
  for (int it = 0; it < GLITERS; ++it) {
    k_prep1<<<dim3(4, NROWS), 256, 0, stream>>>(mag, ar, ai, A1h, A1l);
    k_mm1<<<dim3(7, 64), 256, 0, stream>>>(A1h, A1l, B1h, B1l, frames);
    k_ola<<<(NB * LY + 255) / 256, 256, 0, stream>>>(frames, wsqs, y);
    k_prep2<<<dim3(4, NROWS), 256, 0, stream>>>(y, win, A2h, A2l);
    k_mm2<<<dim3(4, 64), 256, 0, stream>>>(A2h, A2l, B2ch, B2cl, B2sh, B2sl,
                                           ar, ai, tpr, tpi, beta);
  }
  k_prep1<<<dim3(4, NROWS), 256, 0, stream>>>(mag, ar, ai, A1h, A1l);
  k_mm1<<<dim3(7, 64), 256, 0, stream>>>(A1h, A1l, B1h, B1l, frames);
  k_ola<<<(NB * LY + 255) / 256, 256, 0, stream>>>(frames, wsqs, y);

  // normalize
  k_absmax<<<NB, 256, 0, stream>>>(y, peak);
  const float target = (float)pow(10.0, -0.1 / 20.0);
  k_scale<<<(NB * LOUTW + 255) / 256, 256, 0, stream>>>(y, peak, out, target);
}